// Round 4
// baseline (137.610 us; speedup 1.0000x reference)
//
#include <hip/hip_runtime.h>

// Depthwise 4x4 blur ([1/8,3/8,3/8,1/8] separable), stride 2, reflect-pad 1.
// x: [8,128,256,256] f32  ->  y: [8,128,128,128] f32
//
// Block = one (plane, 16-output-row slab). Stage 34 input rows x 256 cols
// (34 KB) into LDS with perfectly coalesced wave-contiguous 1KB row loads;
// compute the separable 4-tap from LDS. Thread = 4 out cols x 2 out rows.
// NOTE: no cross-lane ops (__shfl via ds_bpermute caused nondeterministic
// post-timing divergence in round 3) - LDS staging is replay-safe.

__global__ __launch_bounds__(256) void ds2d_kernel(const float* __restrict__ x,
                                                   float* __restrict__ y) {
    constexpr float k0 = 0.125f, k1 = 0.375f;
    constexpr int W  = 256;              // input width == height
    constexpr int OW = 128;              // output width == height
    constexpr int SLAB  = 16;            // output rows per block
    constexpr int SROWS = 2 * SLAB + 2;  // 34 staged input rows
    constexpr int NQ    = SROWS * 64;    // 2176 float4s to stage

    __shared__ float lds[SROWS * W];     // 34,816 B

    const int b    = blockIdx.x;
    const int nc   = b >> 3;             // fused N*C plane (8*128 = 1024)
    const int slab = b & 7;              // 8 slabs of 16 output rows
    const int oh0  = slab * SLAB;
    const int R0   = 2 * oh0 - 1;        // first (padded-coord) input row

    const float* __restrict__ base = x + (size_t)nc * (W * W);
    const int tid = threadIdx.x;

    // ---- stage: 34 rows x 64 float4, two-phase for MLP, coalesced ----
    float4 st[9];
    int    lofs[9];
    #pragma unroll
    for (int i = 0; i < 9; ++i) {
        const int idx = tid + 256 * i;   // float4 index into the tile
        if (idx < NQ) {
            const int lr = idx >> 6;     // staged row 0..33
            const int c4 = idx & 63;     // float4 col
            int g = R0 + lr;             // reflect-map the global row
            g = (g < 0) ? -g : ((g > W - 1) ? 2 * W - 2 - g : g);
            st[i]   = *reinterpret_cast<const float4*>(base + (g << 8) + (c4 << 2));
            lofs[i] = (lr << 8) + (c4 << 2);
        } else {
            lofs[i] = -1;
        }
    }
    #pragma unroll
    for (int i = 0; i < 9; ++i) {
        if (lofs[i] >= 0)
            *reinterpret_cast<float4*>(&lds[lofs[i]]) = st[i];
    }
    __syncthreads();

    // ---- compute: thread = 4 output cols x 2 output rows ----
    const int t  = tid & 31;             // col quad (128/4)
    const int p  = tid >> 5;             // 0..7 -> output rows 2p, 2p+1
    const int cb = t << 3;               // leftmost input col = 8t
    const int cl = (t == 0)  ? 1     : cb - 1;   // reflect: -1  -> 1
    const int cr = (t == 31) ? W - 2 : cb + 8;   // reflect: 256 -> 254

    float a0[4] = {0.f, 0.f, 0.f, 0.f};
    float a1[4] = {0.f, 0.f, 0.f, 0.f};

    // output row 2p   uses staged rows 4p+0..4p+3, weights [k0,k1,k1,k0]
    // output row 2p+1 uses staged rows 4p+2..4p+5, weights [k0,k1,k1,k0]
    #pragma unroll
    for (int j = 0; j < 6; ++j) {
        const float* row = &lds[(4 * p + j) << 8];
        const float4 f0 = *reinterpret_cast<const float4*>(row + cb);
        const float4 f1 = *reinterpret_cast<const float4*>(row + cb + 4);
        const float  a  = row[cl];
        const float  d  = row[cr];

        const float h0 = k0 * (a    + f0.z) + k1 * (f0.x + f0.y);
        const float h1 = k0 * (f0.y + f1.x) + k1 * (f0.z + f0.w);
        const float h2 = k0 * (f0.w + f1.z) + k1 * (f1.x + f1.y);
        const float h3 = k0 * (f1.y + d   ) + k1 * (f1.z + f1.w);

        if (j < 4) {
            const float w0 = (j == 0 || j == 3) ? k0 : k1;
            a0[0] += w0 * h0; a0[1] += w0 * h1; a0[2] += w0 * h2; a0[3] += w0 * h3;
        }
        if (j >= 2) {
            const float w1 = (j == 2 || j == 5) ? k0 : k1;
            a1[0] += w1 * h0; a1[1] += w1 * h1; a1[2] += w1 * h2; a1[3] += w1 * h3;
        }
    }

    float* __restrict__ o =
        y + ((size_t)nc * OW + oh0 + 2 * p) * OW + (t << 2);
    *reinterpret_cast<float4*>(o)      = make_float4(a0[0], a0[1], a0[2], a0[3]);
    *reinterpret_cast<float4*>(o + OW) = make_float4(a1[0], a1[1], a1[2], a1[3]);
}

extern "C" void kernel_launch(void* const* d_in, const int* in_sizes, int n_in,
                              void* d_out, int out_size, void* d_ws, size_t ws_size,
                              hipStream_t stream) {
    const float* x = (const float*)d_in[0];
    float* y = (float*)d_out;

    // 1024 planes * 8 slabs = 8192 blocks of 256 threads
    ds2d_kernel<<<8192, 256, 0, stream>>>(x, y);
}

// Round 5
// 120.320 us; speedup vs baseline: 1.1437x; 1.1437x over previous
//
#include <hip/hip_runtime.h>

// Depthwise 4x4 blur ([1/8,3/8,3/8,1/8] separable), stride 2, reflect-pad 1.
// x: [8,128,256,256] f32  ->  y: [8,128,128,128] f32
//
// Register-streaming structure (round-2 lineage; LDS version regressed 2x,
// shuffle version was replay-unsafe). Thread = 8 output rows x 8 output
// cols. Streams 18 input rows; per row the 18 needed columns (cb-1..cb+16)
// are loaded with ZERO per-lane redundancy: 4x unaligned float4 + 1x float2
// (dword-aligned; gfx950 HW handles it). Reflect edges = clamped addresses
// + cndmask value permutes, no divergence, no cross-lane ops. Vertical
// reuse in 2 rotating 8-wide accumulators; finished rows stored at once.

__device__ __forceinline__ float4 ld4u(const float* p) {
    float4 v; __builtin_memcpy(&v, p, sizeof(v)); return v;
}
__device__ __forceinline__ float2 ld2u(const float* p) {
    float2 v; __builtin_memcpy(&v, p, sizeof(v)); return v;
}

__global__ __launch_bounds__(256) void ds2d_kernel(const float* __restrict__ x,
                                                   float* __restrict__ y) {
    constexpr float k0 = 0.125f, k1 = 0.375f;
    constexpr int W  = 256;     // input width == height
    constexpr int OW = 128;     // output width == height
    constexpr int HP = 8;       // output rows per thread

    const int nc = blockIdx.x;           // one block per N*C plane (1024)
    const int t  = threadIdx.x & 15;     // col octet (128/8)
    const int s  = threadIdx.x >> 4;     // row strip (128/8)
    const int cb = t << 4;               // leftmost input col = 16t
    const int oh0 = s * HP;

    const float* __restrict__ base = x + (size_t)nc * (W * W);
    float* __restrict__ out = y + ((size_t)nc * OW + oh0) * OW + (t << 3);

    const bool e0  = (t == 0);
    const bool e15 = (t == 15);
    const int a0 = e0  ? 0       : (cb - 1);   // left load col (clamped)
    const int a4 = e15 ? (W - 2) : (cb + 15);  // right float2 col (clamped)

    const int row0 = oh0 * 2 - 1;        // first input row of this strip

    float acc[2][8];                     // rotating accumulators, parity m&1
    #pragma unroll
    for (int p = 0; p < 2; ++p)
        #pragma unroll
        for (int c = 0; c < 8; ++c) acc[p][c] = 0.f;

    #pragma unroll
    for (int rl = 0; rl < 2 * HP + 2; ++rl) {      // 18 input rows
        int r = row0 + rl;
        r = (r < 0) ? -r : ((r > W - 1) ? 2 * W - 2 - r : r);
        const float* __restrict__ row = base + (r << 8);

        const float4 L0 = ld4u(row + a0);
        const float4 L1 = ld4u(row + cb + 3);
        const float4 L2 = ld4u(row + cb + 7);
        const float4 L3 = ld4u(row + cb + 11);
        const float2 L4 = ld2u(row + a4);

        // c[m] = input col cb-1+m; edge lanes permute their own registers
        const float c0  = e0 ? L0.y : L0.x;   // reflect: col -1 -> col 1
        const float c1  = e0 ? L0.x : L0.y;
        const float c2  = e0 ? L0.y : L0.z;
        const float c3  = e0 ? L0.z : L0.w;
        const float c4  = L1.x, c5  = L1.y, c6  = L1.z, c7  = L1.w;
        const float c8  = L2.x, c9  = L2.y, c10 = L2.z, c11 = L2.w;
        const float c12 = L3.x, c13 = L3.y, c14 = L3.z, c15 = L3.w;
        const float c16 = e15 ? L4.y : L4.x;  // col 255
        const float c17 = e15 ? L4.x : L4.y;  // reflect: col 256 -> col 254

        // horizontal 4-tap, out col owb+i uses c[2i..2i+3]
        float h[8];
        h[0] = k0 * (c0  + c3 ) + k1 * (c1  + c2 );
        h[1] = k0 * (c2  + c5 ) + k1 * (c3  + c4 );
        h[2] = k0 * (c4  + c7 ) + k1 * (c5  + c6 );
        h[3] = k0 * (c6  + c9 ) + k1 * (c7  + c8 );
        h[4] = k0 * (c8  + c11) + k1 * (c9  + c10);
        h[5] = k0 * (c10 + c13) + k1 * (c11 + c12);
        h[6] = k0 * (c12 + c15) + k1 * (c13 + c14);
        h[7] = k0 * (c14 + c17) + k1 * (c15 + c16);

        // output row m uses input rows rl = 2m..2m+3, weights [k0,k1,k1,k0]
        const int m = rl >> 1;
        if ((rl & 1) == 0) {
            if (m >= 1) {                 // row m-1, weight k1
                #pragma unroll
                for (int c = 0; c < 8; ++c) acc[(m - 1) & 1][c] += k1 * h[c];
            }
            if (m <= HP - 1) {            // row m, weight k0 (first touch)
                #pragma unroll
                for (int c = 0; c < 8; ++c) acc[m & 1][c] = k0 * h[c];
            }
        } else {
            if (m >= 1) {                 // row m-1, weight k0 -> row done
                float* A = acc[(m - 1) & 1];
                #pragma unroll
                for (int c = 0; c < 8; ++c) A[c] += k0 * h[c];
                float* o = out + (size_t)(m - 1) * OW;
                *reinterpret_cast<float4*>(o)     = make_float4(A[0], A[1], A[2], A[3]);
                *reinterpret_cast<float4*>(o + 4) = make_float4(A[4], A[5], A[6], A[7]);
            }
            if (m <= HP - 1) {            // row m, weight k1
                #pragma unroll
                for (int c = 0; c < 8; ++c) acc[m & 1][c] += k1 * h[c];
            }
        }
    }
}

extern "C" void kernel_launch(void* const* d_in, const int* in_sizes, int n_in,
                              void* d_out, int out_size, void* d_ws, size_t ws_size,
                              hipStream_t stream) {
    const float* x = (const float*)d_in[0];
    float* y = (float*)d_out;

    // one block per plane: 1024 blocks x 256 threads, entire grid resident
    ds2d_kernel<<<1024, 256, 0, stream>>>(x, y);
}

// Round 6
// 116.874 us; speedup vs baseline: 1.1774x; 1.0295x over previous
//
#include <hip/hip_runtime.h>

// Depthwise 4x4 blur ([1/8,3/8,3/8,1/8] separable), stride 2, reflect-pad 1.
// x: [8,128,256,256] f32  ->  y: [8,128,128,128] f32
//
// Register-streaming (round-2 lineage). Thread = 8 output rows x 8 output
// cols. Streams 18 input rows; the 18-col halo window (cb-1..cb+16) is
// covered by SIX 16B-ALIGNED float4 loads (cb-4,cb,cb+4,cb+8,cb+12,cb+16).
// Round-5 lesson: unaligned 16B loads are 2x slower (line-straddling) --
// aligned-only. Reflect edges: clamp 2 edge-load addresses + 2 register
// selects. No cross-lane ops (round-3 replay hazard), no LDS (round-4 2x
// regression). Vertical reuse in 2 rotating 8-wide accumulators.

__global__ __launch_bounds__(256) void ds2d_kernel(const float* __restrict__ x,
                                                   float* __restrict__ y) {
    constexpr float k0 = 0.125f, k1 = 0.375f;
    constexpr int W  = 256;     // input width == height
    constexpr int OW = 128;     // output width == height
    constexpr int HP = 8;       // output rows per thread

    const int nc = blockIdx.x;           // one block per N*C plane (1024)
    const int t  = threadIdx.x & 15;     // col octet (128/8)
    const int s  = threadIdx.x >> 4;     // row strip (128/8)
    const int cb = t << 4;               // leftmost input col of octet = 16t
    const int oh0 = s * HP;

    const float* __restrict__ base = x + (size_t)nc * (W * W);
    float* __restrict__ out = y + ((size_t)nc * OW + oh0) * OW + (t << 3);

    const bool e0  = (t == 0);
    const bool e15 = (t == 15);
    const int colA = e0  ? 0        : cb - 4;   // left halo load (aligned)
    const int colF = e15 ? cb + 12  : cb + 16;  // right halo load (aligned)

    const int row0 = oh0 * 2 - 1;        // first input row of this strip

    float acc[2][8];                     // rotating accumulators, parity m&1
    #pragma unroll
    for (int p = 0; p < 2; ++p)
        #pragma unroll
        for (int c = 0; c < 8; ++c) acc[p][c] = 0.f;

    #pragma unroll
    for (int rl = 0; rl < 2 * HP + 2; ++rl) {      // 18 input rows
        int r = row0 + rl;
        r = (r < 0) ? -r : ((r > W - 1) ? 2 * W - 2 - r : r);
        const float* __restrict__ row = base + (r << 8);

        const float4 A = *reinterpret_cast<const float4*>(row + colA);
        const float4 B = *reinterpret_cast<const float4*>(row + cb);
        const float4 C = *reinterpret_cast<const float4*>(row + cb + 4);
        const float4 D = *reinterpret_cast<const float4*>(row + cb + 8);
        const float4 E = *reinterpret_cast<const float4*>(row + cb + 12);
        const float4 F = *reinterpret_cast<const float4*>(row + colF);

        // halo values with reflect fix-up (col -1 -> 1; col 256 -> 254)
        const float cm1 = e0  ? B.y : A.w;   // col cb-1
        const float c16 = e15 ? E.z : F.x;   // col cb+16

        // horizontal 4-tap: out col owb+i uses cols cb-1+2i .. cb+2+2i
        float h[8];
        h[0] = k0 * (cm1 + B.z) + k1 * (B.x + B.y);
        h[1] = k0 * (B.y + C.x) + k1 * (B.z + B.w);
        h[2] = k0 * (B.w + C.z) + k1 * (C.x + C.y);
        h[3] = k0 * (C.y + D.x) + k1 * (C.z + C.w);
        h[4] = k0 * (C.w + D.z) + k1 * (D.x + D.y);
        h[5] = k0 * (D.y + E.x) + k1 * (D.z + D.w);
        h[6] = k0 * (D.w + E.z) + k1 * (E.x + E.y);
        h[7] = k0 * (E.y + c16) + k1 * (E.z + E.w);

        // output row m uses input rows rl = 2m..2m+3, weights [k0,k1,k1,k0]
        const int m = rl >> 1;
        if ((rl & 1) == 0) {
            if (m >= 1) {                 // row m-1, weight k1
                #pragma unroll
                for (int c = 0; c < 8; ++c) acc[(m - 1) & 1][c] += k1 * h[c];
            }
            if (m <= HP - 1) {            // row m, weight k0 (first touch)
                #pragma unroll
                for (int c = 0; c < 8; ++c) acc[m & 1][c] = k0 * h[c];
            }
        } else {
            if (m >= 1) {                 // row m-1, weight k0 -> row done
                float* Aacc = acc[(m - 1) & 1];
                #pragma unroll
                for (int c = 0; c < 8; ++c) Aacc[c] += k0 * h[c];
                float* o = out + (size_t)(m - 1) * OW;
                *reinterpret_cast<float4*>(o)     = make_float4(Aacc[0], Aacc[1], Aacc[2], Aacc[3]);
                *reinterpret_cast<float4*>(o + 4) = make_float4(Aacc[4], Aacc[5], Aacc[6], Aacc[7]);
            }
            if (m <= HP - 1) {            // row m, weight k1
                #pragma unroll
                for (int c = 0; c < 8; ++c) acc[m & 1][c] += k1 * h[c];
            }
        }
    }
}

extern "C" void kernel_launch(void* const* d_in, const int* in_sizes, int n_in,
                              void* d_out, int out_size, void* d_ws, size_t ws_size,
                              hipStream_t stream) {
    const float* x = (const float*)d_in[0];
    float* y = (float*)d_out;

    // 1024 planes, one block per plane: 16 strips x 16 col-octets = 256 thr
    ds2d_kernel<<<1024, 256, 0, stream>>>(x, y);
}

// Round 7
// 71.408 us; speedup vs baseline: 1.9271x; 1.6367x over previous
//
#include <hip/hip_runtime.h>

// Depthwise 4x4 blur ([1/8,3/8,3/8,1/8] separable), stride 2, reflect-pad 1.
// x: [8,128,256,256] f32  ->  y: [8,128,128,128] f32
//
// Round-2 structure (known 71.5us): thread = 4 outcols x 8 outrows,
// t=tid&31 so 32 lanes are contiguous within a row (clean ~16-line/instr
// coalescing). ONE change: the two scalar edge loads (128B-stride scatters,
// ~64 lines/instr -- the round2->3 10us delta) become two 8B-aligned float2
// loads at cb-2 and cb+8 (clean 32B-stride pattern). Reflect handled purely
// by address clamps: t==0 -> load col 0, .y = col 1 = reflect(-1);
// t==31 -> load col 254, .x = col 254 = reflect(256). No selects, no
// cross-lane ops (round-3 replay hazard), no LDS (round-4 regression),
// no unaligned 16B (round-5), no multi-strip wave spread (round-6).

__global__ __launch_bounds__(256) void ds2d_kernel(const float* __restrict__ x,
                                                   float* __restrict__ y) {
    constexpr float k0 = 0.125f, k1 = 0.375f;
    constexpr int W  = 256;     // input width == height
    constexpr int OW = 128;     // output width == height
    constexpr int HP = 8;       // output rows per thread

    const int tid = blockIdx.x * 256 + threadIdx.x;
    const int t   = tid & 31;           // col-quad within output row (128/4)
    const int s   = (tid >> 5) & 15;    // row strip (128/8)
    const int nc  = tid >> 9;           // fused N*C plane (8*128 = 1024)
    const int cb  = t << 3;             // leftmost input col = 8t
    const int oh0 = s * HP;

    const float* __restrict__ base = x + (size_t)nc * (W * W);
    float* __restrict__ out = y + ((size_t)nc * OW + oh0) * OW + (t << 2);

    // clamped halo-load columns; reflect falls out of the clamp exactly
    const int colA = (t == 0)  ? 0       : cb - 2;   // float2: .y = col cb-1 (or reflect)
    const int colD = (t == 31) ? W - 2   : cb + 8;   // float2: .x = col cb+8 (or reflect)

    const int row0 = oh0 * 2 - 1;       // first input row of this strip

    float acc[2][4];                    // rotating accumulators, parity = m&1
    #pragma unroll
    for (int p = 0; p < 2; ++p)
        #pragma unroll
        for (int c = 0; c < 4; ++c) acc[p][c] = 0.f;

    #pragma unroll
    for (int rl = 0; rl < 2 * HP + 2; ++rl) {      // 18 input rows
        int r = row0 + rl;
        r = (r < 0) ? -r : ((r > W - 1) ? 2 * W - 2 - r : r);
        const float* __restrict__ row = base + (r << 8);

        const float2 A  = *reinterpret_cast<const float2*>(row + colA);
        const float4 f0 = *reinterpret_cast<const float4*>(row + cb);
        const float4 f1 = *reinterpret_cast<const float4*>(row + cb + 4);
        const float2 D  = *reinterpret_cast<const float2*>(row + colD);

        const float a = A.y;            // col cb-1 (reflect-correct at t==0)
        const float d = D.x;            // col cb+8 (reflect-correct at t==31)

        // horizontal 4-tap at the 4 output positions (computed once per row)
        const float h0 = k0 * (a    + f0.z) + k1 * (f0.x + f0.y);
        const float h1 = k0 * (f0.y + f1.x) + k1 * (f0.z + f0.w);
        const float h2 = k0 * (f0.w + f1.z) + k1 * (f1.x + f1.y);
        const float h3 = k0 * (f1.y + d   ) + k1 * (f1.z + f1.w);

        // output row m uses input rows rl = 2m..2m+3, weights [k0,k1,k1,k0]
        const int  m   = rl >> 1;
        const bool odd = (rl & 1) != 0;
        if (!odd) {
            if (m >= 1) {               // row m-1, weight k1
                float* Aa = acc[(m - 1) & 1];
                Aa[0] += k1 * h0; Aa[1] += k1 * h1; Aa[2] += k1 * h2; Aa[3] += k1 * h3;
            }
            if (m <= HP - 1) {          // row m, weight k0 (first touch)
                float* Aa = acc[m & 1];
                Aa[0] = k0 * h0; Aa[1] = k0 * h1; Aa[2] = k0 * h2; Aa[3] = k0 * h3;
            }
        } else {
            if (m >= 1) {               // row m-1, weight k0 -> row done
                float* Aa = acc[(m - 1) & 1];
                Aa[0] += k0 * h0; Aa[1] += k0 * h1; Aa[2] += k0 * h2; Aa[3] += k0 * h3;
                float4 o = make_float4(Aa[0], Aa[1], Aa[2], Aa[3]);
                *reinterpret_cast<float4*>(out + (size_t)(m - 1) * OW) = o;
            }
            if (m <= HP - 1) {          // row m, weight k1
                float* Aa = acc[m & 1];
                Aa[0] += k1 * h0; Aa[1] += k1 * h1; Aa[2] += k1 * h2; Aa[3] += k1 * h3;
            }
        }
    }
}

extern "C" void kernel_launch(void* const* d_in, const int* in_sizes, int n_in,
                              void* d_out, int out_size, void* d_ws, size_t ws_size,
                              hipStream_t stream) {
    const float* x = (const float*)d_in[0];
    float* y = (float*)d_out;

    // 1024 planes * 16 strips * 32 col-quads = 524,288 threads, exact
    const int block = 256;
    const int grid = (1024 * 16 * 32) / block;   // 2048
    ds2d_kernel<<<grid, block, 0, stream>>>(x, y);
}

// Round 8
// 62.297 us; speedup vs baseline: 2.2089x; 1.1462x over previous
//
#include <hip/hip_runtime.h>

// Depthwise 4x4 blur ([1/8,3/8,3/8,1/8] separable), stride 2, reflect-pad 1.
// x: [8,128,256,256] f32  ->  y: [8,128,128,128] f32
//
// Round-7 structure (thread = 4 outcols x 8 outrows, 32 lanes contiguous
// per row, 2048 blocks x 256). ONE change: the two edge loads per row are
// replaced by an intra-wave LDS exchange -- per row each thread writes
// {f1.w, f0.x} (8B) to its own slot and reads its +-1 neighbors' slots.
// The exchange never crosses a wave (t=tid&31; t==0/31 edges resolve from
// the thread's OWN registers via reflect selects), so no barrier is needed:
// one wave's LDS ops complete in issue order. Slots are per-threadIdx ->
// disjoint ownership -> replay-deterministic (unlike round-3's __shfl).
// History: LDS full staging = 137us (r4), unaligned 16B = 120us (r5),
// 16-lane tiles = 117us (r6), scalar/float2 edge loads = 71.5us (r2/r7),
// __shfl exchange = 61.5us but replay-UNSAFE (r3).

__global__ __launch_bounds__(256) void ds2d_kernel(const float* __restrict__ x,
                                                   float* __restrict__ y) {
    constexpr float k0 = 0.125f, k1 = 0.375f;
    constexpr int W  = 256;     // input width == height
    constexpr int OW = 128;     // output width == height
    constexpr int HP = 8;       // output rows per thread

    __shared__ float2 buf[256]; // per-thread exchange slot: {f1.w, f0.x}

    const int tid = blockIdx.x * 256 + threadIdx.x;
    const int t   = tid & 31;           // col-quad within output row (128/4)
    const int s   = (tid >> 5) & 15;    // row strip (128/8)
    const int nc  = tid >> 9;           // fused N*C plane (8*128 = 1024)
    const int cb  = t << 3;             // leftmost input col = 8t
    const int oh0 = s * HP;

    const float* __restrict__ base = x + (size_t)nc * (W * W);
    float* __restrict__ out = y + ((size_t)nc * OW + oh0) * OW + (t << 2);

    const bool e0  = (t == 0);
    const bool e31 = (t == 31);
    const int  lx  = threadIdx.x;
    const int  im  = e0  ? lx : lx - 1;  // left neighbor slot (clamped; value
    const int  ip  = e31 ? lx : lx + 1;  // right neighbor slot  discarded at edge)

    const int row0 = oh0 * 2 - 1;       // first input row of this strip

    float acc[2][4];                    // rotating accumulators, parity = m&1
    #pragma unroll
    for (int p = 0; p < 2; ++p)
        #pragma unroll
        for (int c = 0; c < 4; ++c) acc[p][c] = 0.f;

    #pragma unroll
    for (int rl = 0; rl < 2 * HP + 2; ++rl) {      // 18 input rows
        int r = row0 + rl;
        r = (r < 0) ? -r : ((r > W - 1) ? 2 * W - 2 - r : r);
        const float* __restrict__ row = base + (r << 8);

        const float4 f0 = *reinterpret_cast<const float4*>(row + cb);
        const float4 f1 = *reinterpret_cast<const float4*>(row + cb + 4);

        // intra-wave halo exchange through LDS (no barrier: same-wave order)
        buf[lx] = make_float2(f1.w, f0.x);
        const float a_n = buf[im].x;     // lane t-1's f1.w == row[cb-1]
        const float d_n = buf[ip].y;     // lane t+1's f0.x == row[cb+8]
        const float a = e0  ? f0.y : a_n;   // reflect: col -1  -> col 1
        const float d = e31 ? f1.z : d_n;   // reflect: col 256 -> col 254

        // horizontal 4-tap at the 4 output positions (computed once per row)
        const float h0 = k0 * (a    + f0.z) + k1 * (f0.x + f0.y);
        const float h1 = k0 * (f0.y + f1.x) + k1 * (f0.z + f0.w);
        const float h2 = k0 * (f0.w + f1.z) + k1 * (f1.x + f1.y);
        const float h3 = k0 * (f1.y + d   ) + k1 * (f1.z + f1.w);

        // output row m uses input rows rl = 2m..2m+3, weights [k0,k1,k1,k0]
        const int  m   = rl >> 1;
        const bool odd = (rl & 1) != 0;
        if (!odd) {
            if (m >= 1) {               // row m-1, weight k1
                float* Aa = acc[(m - 1) & 1];
                Aa[0] += k1 * h0; Aa[1] += k1 * h1; Aa[2] += k1 * h2; Aa[3] += k1 * h3;
            }
            if (m <= HP - 1) {          // row m, weight k0 (first touch)
                float* Aa = acc[m & 1];
                Aa[0] = k0 * h0; Aa[1] = k0 * h1; Aa[2] = k0 * h2; Aa[3] = k0 * h3;
            }
        } else {
            if (m >= 1) {               // row m-1, weight k0 -> row done
                float* Aa = acc[(m - 1) & 1];
                Aa[0] += k0 * h0; Aa[1] += k0 * h1; Aa[2] += k0 * h2; Aa[3] += k0 * h3;
                float4 o = make_float4(Aa[0], Aa[1], Aa[2], Aa[3]);
                *reinterpret_cast<float4*>(out + (size_t)(m - 1) * OW) = o;
            }
            if (m <= HP - 1) {          // row m, weight k1
                float* Aa = acc[m & 1];
                Aa[0] += k1 * h0; Aa[1] += k1 * h1; Aa[2] += k1 * h2; Aa[3] += k1 * h3;
            }
        }
    }
}

extern "C" void kernel_launch(void* const* d_in, const int* in_sizes, int n_in,
                              void* d_out, int out_size, void* d_ws, size_t ws_size,
                              hipStream_t stream) {
    const float* x = (const float*)d_in[0];
    float* y = (float*)d_out;

    // 1024 planes * 16 strips * 32 col-quads = 524,288 threads, exact
    const int block = 256;
    const int grid = (1024 * 16 * 32) / block;   // 2048
    ds2d_kernel<<<grid, block, 0, stream>>>(x, y);
}